// Round 16
// baseline (283.551 us; speedup 1.0000x reference)
//
#include <hip/hip_runtime.h>
#include <math.h>

typedef unsigned short u16;
typedef __attribute__((ext_vector_type(8))) short bf16x8;
typedef __attribute__((ext_vector_type(4))) float f32x4;

#define C_DIM 1024
#define N_TOK 2048

static __device__ __forceinline__ u16 f2bf(float f) {
  union { float f; unsigned u; } v; v.f = f;
  unsigned r = v.u + 0x7fff + ((v.u >> 16) & 1);
  return (u16)(r >> 16);
}

// packed f32x2 -> bf16x2 (RNE, same rounding as f2bf) in ONE VALU op
static __device__ __forceinline__ unsigned cvt_pk_bf16(float lo, float hi) {
  unsigned r;
  asm("v_cvt_pk_bf16_f32 %0, %1, %2" : "=v"(r) : "v"(lo), "v"(hi));
  return r;
}

// ---------------- wbar[c][d] = mean over heads of k-weights ---------------
// tiny opening launch: wbar must precede fused_pre (metric reads it there;
// intra-launch producer->consumer is forbidden — R13 lesson).
__global__ __launch_bounds__(256) void wbar_kernel(
    const float* __restrict__ qkv_w, float* __restrict__ wbar)
{
  const int idx = blockIdx.x * 256 + threadIdx.x;   // c*64 + d
  const int c = idx >> 6, d = idx & 63;
  float s = 0.f;
  #pragma unroll
  for (int h = 0; h < 16; h++)
    s += qkv_w[(size_t)c * 3072 + 1024 + h * 64 + d];
  wbar[idx] = s * (1.0f / 16.0f);
}

// ---------------- transpose body: W[K][N] tile (by,bx) -> WT[N][K] --------
static __device__ __forceinline__ void conv_body(
    const float* __restrict__ W, u16* __restrict__ WT, int K, int N,
    int bx, int by, float (*tile)[33], int tx, int ty)
{
  #pragma unroll
  for (int i = 0; i < 32; i += 8)
    tile[ty + i][tx] = W[(size_t)(by + ty + i) * N + bx + tx];
  __syncthreads();
  #pragma unroll
  for (int i = 0; i < 32; i += 8)
    WT[(size_t)(bx + ty + i) * K + by + tx] = f2bf(tile[tx][ty + i]);
}

// ---- fused opening launch: METRIC(inline LN1) + LN1 + ALL weight converts
// bid [0,512): metric — recomputes LN1 for its own 4 rows from x (fp32),
//   dots with wbar. VALU-serial chain (~15us) runs FIRST, shadowed by the
//   14336 memory-bound convert/LN blocks (R15: metric cost +15us in any
//   compute launch; here it overlaps streaming work).
// bid [512,2560): LN1 -> bf16 only (fp32 hf DELETED — metric was its only
//   consumer). [2560,5632) qkv^T | [5632,6656) proj^T | [6656,10752) fc1^T
//   | [10752,14848) fc2^T.
__global__ __launch_bounds__(256) void fused_pre_kernel(
    const float* __restrict__ x, const float* __restrict__ ln1_g,
    const float* __restrict__ ln1_b, u16* __restrict__ b_h,
    const float* __restrict__ qkv_w, u16* __restrict__ w_qkvT,
    const float* __restrict__ proj_w, u16* __restrict__ w_projT,
    const float* __restrict__ fc1_w, u16* __restrict__ w_fc1T,
    const float* __restrict__ fc2_w, u16* __restrict__ w_fc2T,
    const float* __restrict__ wbar, float* __restrict__ metric)
{
  __shared__ __attribute__((aligned(16))) char smem[16384];
  __shared__ float rs[4], rss[4];
  const int bid = blockIdx.x;
  const int t = threadIdx.x;

  if (bid < 512) {           // ---- metric with inline LN1 (fp32) ----
    float (*hs)[1024] = (float(*)[1024])smem;
    const int w = t >> 6;
    const int lane = t & 63;
    const int n0 = bid * 4;
    // wave w computes LN1 of row n0+w (16 elems/lane)
    const float* xr = x + (size_t)(n0 + w) * C_DIM;
    float4 xv0 = *(const float4*)(xr + lane * 4);
    float4 xv1 = *(const float4*)(xr + 256 + lane * 4);
    float4 xv2 = *(const float4*)(xr + 512 + lane * 4);
    float4 xv3 = *(const float4*)(xr + 768 + lane * 4);
    float s  = (xv0.x + xv0.y + xv0.z + xv0.w) + (xv1.x + xv1.y + xv1.z + xv1.w)
             + (xv2.x + xv2.y + xv2.z + xv2.w) + (xv3.x + xv3.y + xv3.z + xv3.w);
    float ss = (xv0.x*xv0.x + xv0.y*xv0.y + xv0.z*xv0.z + xv0.w*xv0.w)
             + (xv1.x*xv1.x + xv1.y*xv1.y + xv1.z*xv1.z + xv1.w*xv1.w)
             + (xv2.x*xv2.x + xv2.y*xv2.y + xv2.z*xv2.z + xv2.w*xv2.w)
             + (xv3.x*xv3.x + xv3.y*xv3.y + xv3.z*xv3.z + xv3.w*xv3.w);
    #pragma unroll
    for (int off = 1; off < 64; off <<= 1) {
      s  += __shfl_xor(s, off);
      ss += __shfl_xor(ss, off);
    }
    const float mean = s * (1.0f / C_DIM);
    const float var  = ss * (1.0f / C_DIM) - mean * mean;
    const float inv  = rsqrtf(var + 1e-5f);
    #pragma unroll
    for (int k = 0; k < 4; k++) {
      const float4 xv = (k == 0) ? xv0 : (k == 1) ? xv1 : (k == 2) ? xv2 : xv3;
      float4 gv = *(const float4*)(ln1_g + k * 256 + lane * 4);
      float4 bv = *(const float4*)(ln1_b + k * 256 + lane * 4);
      float4 o;
      o.x = (xv.x - mean) * inv * gv.x + bv.x;
      o.y = (xv.y - mean) * inv * gv.y + bv.y;
      o.z = (xv.z - mean) * inv * gv.z + bv.z;
      o.w = (xv.w - mean) * inv * gv.w + bv.w;
      *(float4*)&hs[w][k * 256 + lane * 4] = o;
    }
    __syncthreads();
    // metric dot (verbatim accumulation order)
    const int d = t & 63;
    const float* hsw = hs[t >> 6];
    float a0=0,a1=0,a2=0,a3=0,a4=0,a5=0,a6=0,a7=0;
    for (int c = 0; c < 1024; c += 8) {
      a0 += hsw[c+0] * wbar[(c+0)*64 + d];
      a1 += hsw[c+1] * wbar[(c+1)*64 + d];
      a2 += hsw[c+2] * wbar[(c+2)*64 + d];
      a3 += hsw[c+3] * wbar[(c+3)*64 + d];
      a4 += hsw[c+4] * wbar[(c+4)*64 + d];
      a5 += hsw[c+5] * wbar[(c+5)*64 + d];
      a6 += hsw[c+6] * wbar[(c+6)*64 + d];
      a7 += hsw[c+7] * wbar[(c+7)*64 + d];
    }
    float sm = ((a0+a1)+(a2+a3)) + ((a4+a5)+(a6+a7));
    float sq = sm * sm;
    #pragma unroll
    for (int off = 1; off < 64; off <<= 1) sq += __shfl_xor(sq, off);
    metric[(size_t)(n0 + (t >> 6)) * 64 + d] = sm / sqrtf(sq);
    return;
  }

  const int tx = t & 31, ty = t >> 5;
  float (*tile)[33] = (float(*)[33])smem;
  if (bid < 2560) {            // ---- LN1 -> bf16 (verbatim reduction) ----
    const int row = bid - 512;
    const float* xr = x + (size_t)row * C_DIM;
    float4 xv = *(const float4*)(xr + t * 4);
    float s  = xv.x + xv.y + xv.z + xv.w;
    float ss = xv.x*xv.x + xv.y*xv.y + xv.z*xv.z + xv.w*xv.w;
    #pragma unroll
    for (int off = 1; off < 64; off <<= 1) {
      s  += __shfl_xor(s, off);
      ss += __shfl_xor(ss, off);
    }
    const int w = t >> 6;
    if ((t & 63) == 0) { rs[w] = s; rss[w] = ss; }
    __syncthreads();
    s  = rs[0] + rs[1] + rs[2] + rs[3];
    ss = rss[0] + rss[1] + rss[2] + rss[3];
    const float mean = s * (1.0f / C_DIM);
    const float var  = ss * (1.0f / C_DIM) - mean * mean;
    const float inv  = rsqrtf(var + 1e-5f);
    float4 gv = *(const float4*)(ln1_g + t * 4);
    float4 bv = *(const float4*)(ln1_b + t * 4);
    float4 o;
    o.x = (xv.x - mean) * inv * gv.x + bv.x;
    o.y = (xv.y - mean) * inv * gv.y + bv.y;
    o.z = (xv.z - mean) * inv * gv.z + bv.z;
    o.w = (xv.w - mean) * inv * gv.w + bv.w;
    ushort4 o4;
    o4.x = f2bf(o.x); o4.y = f2bf(o.y); o4.z = f2bf(o.z); o4.w = f2bf(o.w);
    *(ushort4*)(b_h + (size_t)row * C_DIM + t * 4) = o4;
  } else if (bid < 5632) {     // ---- qkv^T: 96 x 32 tiles ----
    const int b2 = bid - 2560;
    conv_body(qkv_w, w_qkvT, 1024, 3072, (b2 % 96) * 32, (b2 / 96) * 32, tile, tx, ty);
  } else if (bid < 6656) {     // ---- proj^T: 32 x 32 tiles ----
    const int b2 = bid - 5632;
    conv_body(proj_w, w_projT, 1024, 1024, (b2 % 32) * 32, (b2 / 32) * 32, tile, tx, ty);
  } else if (bid < 10752) {    // ---- fc1^T: 128 x 32 tiles ----
    const int b2 = bid - 6656;
    conv_body(fc1_w, w_fc1T, 1024, 4096, (b2 % 128) * 32, (b2 / 128) * 32, tile, tx, ty);
  } else {                     // ---- fc2^T: 32 x 128 tiles ----
    const int b2 = bid - 10752;
    conv_body(fc2_w, w_fc2T, 4096, 1024, (b2 % 32) * 32, (b2 / 32) * 32, tile, tx, ty);
  }
}

// -------- fused divide + LN2: v = xm/size -> outx/outs, LN(v) -> h2 -------
__global__ __launch_bounds__(256) void divide_ln2_kernel(
    const float* __restrict__ xm, const float* __restrict__ sizem,
    const float* __restrict__ g, const float* __restrict__ b,
    float* __restrict__ outx, float* __restrict__ outs,
    u16* __restrict__ h2)
{
  const int row = blockIdx.x;
  const int t = threadIdx.x;
  const float sz = sizem[row];
  float4 xv = *(const float4*)(xm + (size_t)row * C_DIM + t * 4);
  xv.x = xv.x / sz; xv.y = xv.y / sz; xv.z = xv.z / sz; xv.w = xv.w / sz;
  *(float4*)(outx + (size_t)row * C_DIM + t * 4) = xv;
  if (t == 0) outs[row] = sz;
  float s  = xv.x + xv.y + xv.z + xv.w;
  float ss = xv.x*xv.x + xv.y*xv.y + xv.z*xv.z + xv.w*xv.w;
  #pragma unroll
  for (int off = 1; off < 64; off <<= 1) {
    s  += __shfl_xor(s, off);
    ss += __shfl_xor(ss, off);
  }
  __shared__ float rs[4], rss[4];
  const int w = t >> 6;
  if ((t & 63) == 0) { rs[w] = s; rss[w] = ss; }
  __syncthreads();
  s  = rs[0] + rs[1] + rs[2] + rs[3];
  ss = rss[0] + rss[1] + rss[2] + rss[3];
  const float mean = s * (1.0f / C_DIM);
  const float var  = ss * (1.0f / C_DIM) - mean * mean;
  const float inv  = rsqrtf(var + 1e-5f);
  float4 gv = *(const float4*)(g + t * 4);
  float4 bv = *(const float4*)(b + t * 4);
  float4 o;
  o.x = (xv.x - mean) * inv * gv.x + bv.x;
  o.y = (xv.y - mean) * inv * gv.y + bv.y;
  o.z = (xv.z - mean) * inv * gv.z + bv.z;
  o.w = (xv.w - mean) * inv * gv.w + bv.w;
  ushort4 o4;
  o4.x = f2bf(o.x); o4.y = f2bf(o.y); o4.z = f2bf(o.z); o4.w = f2bf(o.w);
  *(ushort4*)(h2 + (size_t)row * C_DIM + t * 4) = o4;
}

// ---------------- bf16 MFMA GEMM: C[M,N] = A[M,K] @ BT[N,K]^T -------------
// R6 geometry (proven): BN=64, LDS double-buffer, one barrier/iter.
// SPLIT>1: partitioned slices. VTOUT (R14-verified): blocks with bn>=2048
// (V-third of QKV GEMM) store the C-tile TRANSPOSED to vt[d][token] via an
// LDS transpose (dead As staging, stride-132 pad), same RNE bf16 values.
template<int BM, int BN, int SPLIT, bool BIAS, bool GELU, bool RES, bool OUT_BF16, bool VTOUT = false>
__global__ __launch_bounds__(256) void gemm_mfma(
    const u16* __restrict__ A,   // [>=gridDim.y*BM][K] bf16 (readable padding)
    const u16* __restrict__ BT,  // [N][K] bf16
    const float* __restrict__ bias, const float* __restrict__ res,
    void* __restrict__ Cout, int M, int N, int K)
{
  constexpr int TM = BM / 32;                 // 16x16 tiles per wave (rows)
  constexpr int TN = BN / 32;                 // 16x16 tiles per wave (cols)
  __shared__ u16 As[2][BM * 64] __attribute__((aligned(16)));
  __shared__ u16 Bs[2][BN * 64] __attribute__((aligned(16)));
  const int tid  = threadIdx.x;
  const int lane = tid & 63;
  const int w    = tid >> 6;
  const int bm = blockIdx.y * BM;
  const int bn = blockIdx.x * BN;
  const int wm = (w >> 1) * (BM / 2);
  const int wn = (w & 1) * (BN / 2);

  f32x4 acc[TM][TN] = {};

  const int rl = lane >> 3;                 // row-in-8-group
  const int cg = (lane & 7) ^ rl;           // swizzled source chunk

  const int kb = (K / SPLIT) * blockIdx.z;
  const int ke = kb + K / SPLIT;

#define GEMM_STAGE(buf, k0_)                                                   \
  {                                                                            \
    _Pragma("unroll")                                                          \
    for (int i = 0; i < BM / 32; i++) {                                        \
      const int r = w * (BM / 4) + i * 8 + rl;                                 \
      __builtin_amdgcn_global_load_lds(                                        \
          (const __attribute__((address_space(1))) void*)(A + (size_t)(bm + r) * K + (k0_) + cg * 8), \
          (__attribute__((address_space(3))) void*)(&As[buf][(w * (BM / 4) + i * 8) * 64]), \
          16, 0, 0);                                                           \
    }                                                                          \
    _Pragma("unroll")                                                          \
    for (int i = 0; i < BN / 32; i++) {                                        \
      const int r = w * (BN / 4) + i * 8 + rl;                                 \
      __builtin_amdgcn_global_load_lds(                                        \
          (const __attribute__((address_space(1))) void*)(BT + (size_t)(bn + r) * K + (k0_) + cg * 8), \
          (__attribute__((address_space(3))) void*)(&Bs[buf][(w * (BN / 4) + i * 8) * 64]), \
          16, 0, 0);                                                           \
    }                                                                          \
  }

  // prologue: stage first K-tile into buffer 0
  GEMM_STAGE(0, kb);
  __syncthreads();

  int cur = 0;
  for (int k0 = kb; k0 < ke; k0 += 64) {
    // issue next tile's loads into the other buffer (overlap compute)
    if (k0 + 64 < ke) GEMM_STAGE(cur ^ 1, k0 + 64);

    #pragma unroll
    for (int kk = 0; kk < 2; kk++) {
      bf16x8 af[TM], bfr[TN];
      const int slot = (kk * 4 + (lane >> 4)) ^ (lane & 7);
      #pragma unroll
      for (int i = 0; i < TM; i++)
        af[i] = *(const bf16x8*)&As[cur][(wm + i * 16 + (lane & 15)) * 64 + slot * 8];
      #pragma unroll
      for (int j = 0; j < TN; j++)
        bfr[j] = *(const bf16x8*)&Bs[cur][(wn + j * 16 + (lane & 15)) * 64 + slot * 8];
      __builtin_amdgcn_s_setprio(1);
      #pragma unroll
      for (int i = 0; i < TM; i++)
        #pragma unroll
        for (int j = 0; j < TN; j++)
          acc[i][j] = __builtin_amdgcn_mfma_f32_16x16x32_bf16(af[i], bfr[j], acc[i][j], 0, 0, 0);
      __builtin_amdgcn_s_setprio(0);
    }
    __syncthreads();
    cur ^= 1;
  }
#undef GEMM_STAGE

  if constexpr (VTOUT) {
    if (bn >= 2048) {
      // transposed V store: tile[n_local][m_local], stride 132 u16
      u16* tile = (u16*)&As[0][0];
      #pragma unroll
      for (int i = 0; i < TM; i++)
        #pragma unroll
        for (int j = 0; j < TN; j++) {
          const int nl = wn + j * 16 + (lane & 15);
          const int mb = wm + i * 16 + (lane >> 4) * 4;
          uint2 pk;
          pk.x = cvt_pk_bf16(acc[i][j][0], acc[i][j][1]);
          pk.y = cvt_pk_bf16(acc[i][j][2], acc[i][j][3]);
          *(uint2*)&tile[nl * 132 + mb] = pk;
        }
      __syncthreads();
      u16* vt = (u16*)res;               // vt base smuggled via res
      const int row = tid >> 2;          // 0..63  (n_local)
      const int cc  = (tid & 3) * 32;    // m chunk
      #pragma unroll
      for (int c4 = 0; c4 < 8; c4++) {
        ushort4 v4 = *(const ushort4*)&tile[row * 132 + cc + c4 * 4];
        *(ushort4*)&vt[(size_t)(bn - 2048 + row) * 2048 + bm + cc + c4 * 4] = v4;
      }
      return;
    }
  }

  if constexpr (SPLIT > 1) {
    // partitioned plain stores: slice z at Cf + z*M*N (sole writer)
    float* Cf = (float*)Cout + (size_t)blockIdx.z * ((size_t)M * N);
    #pragma unroll
    for (int i = 0; i < TM; i++)
      #pragma unroll
      for (int r = 0; r < 4; r++) {
        const int m = bm + wm + i * 16 + (lane >> 4) * 4 + r;
        if (m < M) {
          #pragma unroll
          for (int j = 0; j < TN; j++) {
            const int n = bn + wn + j * 16 + (lane & 15);
            Cf[(size_t)m * N + n] = acc[i][j][r];
          }
        }
      }
  } else {
    #pragma unroll
    for (int i = 0; i < TM; i++) {
      #pragma unroll
      for (int r = 0; r < 4; r++) {
        const int m = bm + wm + i * 16 + (lane >> 4) * 4 + r;
        if (m < M) {
          #pragma unroll
          for (int j = 0; j < TN; j++) {
            const int n = bn + wn + j * 16 + (lane & 15);
            float v = acc[i][j][r];
            if (BIAS) v += bias[n];
            if (GELU) v = 0.5f * v * (1.0f + erff(v * 0.70710678118654752f));
            if (RES)  v += res[(size_t)m * N + n];
            if (OUT_BF16) ((u16*)Cout)[(size_t)m * N + n] = f2bf(v);
            else          ((float*)Cout)[(size_t)m * N + n] = v;
          }
        }
      }
    }
  }
}

// ------ split-K epilogue: out += sum(4 slices) + bias (in-place res) ------
__global__ __launch_bounds__(256) void splitk_epilogue_kernel(
    const float* __restrict__ acc, const float* __restrict__ bias,
    float* __restrict__ out, int M)
{
  const int idx = blockIdx.x * 256 + threadIdx.x;   // float4 index
  if (idx >= M * 256) return;
  const size_t S = (size_t)M * 256;                 // slice stride in float4
  const float4* a4 = (const float4*)acc;
  float4 a0 = a4[idx], a1 = a4[idx + S], a2 = a4[idx + 2 * S], a3 = a4[idx + 3 * S];
  float4 bv = *(const float4*)(bias + (idx & 255) * 4);
  float4 o = *(const float4*)(out + (size_t)idx * 4);
  o.x += (a0.x + a1.x) + (a2.x + a3.x) + bv.x;
  o.y += (a0.y + a1.y) + (a2.y + a3.y) + bv.y;
  o.z += (a0.z + a1.z) + (a2.z + a3.z) + bv.z;
  o.w += (a0.w + a1.w) + (a2.w + a3.w) + bv.w;
  *(float4*)(out + (size_t)idx * 4) = o;
}

// ---------------- MFMA flash attention (pure, R4/R12 proven form) ---------
template<int SPLIT>
__global__ __launch_bounds__(256) void attn_mfma(
    const u16* __restrict__ qkv, const u16* __restrict__ vt,
    const float* __restrict__ sz, float* __restrict__ opart,
    float* __restrict__ lpart)
{
  const int h   = blockIdx.y;
  const int q0  = blockIdx.x * 64;
  const int tid = threadIdx.x;
  const int lane = tid & 63;
  const int w    = tid >> 6;
  const int col  = lane & 15;
  const int quad = lane >> 4;

  __shared__ u16 Ks [2][64 * 64] __attribute__((aligned(16)));
  __shared__ u16 Vts[64 * 64] __attribute__((aligned(16)));
  __shared__ u16 Ps[4][16 * 72] __attribute__((aligned(16)));
  __shared__ float lball[N_TOK / SPLIT];

  bf16x8 qf[2];
  {
    const u16* qp = qkv + (size_t)(q0 + w * 16 + col) * 3072 + h * 64 + quad * 8;
    qf[0] = *(const bf16x8*)(qp);
    qf[1] = *(const bf16x8*)(qp + 32);
  }

  float l_lane = 0.f;
  f32x4 oacc[4] = {};

  const int rl = lane >> 3;
  const int cg = (lane & 7) ^ rl;
  const int kb = blockIdx.z * (N_TOK / SPLIT);
  const int ke = kb + N_TOK / SPLIT;

  constexpr float kScaleLog2e = 0.18033688011112042f;  // 0.125*log2(e)

  #pragma unroll
  for (int i = 0; i < 2; i++) {
    const int r = w * 16 + i * 8 + rl;
    __builtin_amdgcn_global_load_lds(
        (const __attribute__((address_space(1))) void*)(qkv + (size_t)(kb + r) * 3072 + 1024 + h * 64 + cg * 8),
        (__attribute__((address_space(3))) void*)(&Ks[0][(w * 16 + i * 8) * 64]),
        16, 0, 0);
    __builtin_amdgcn_global_load_lds(
        (const __attribute__((address_space(1))) void*)(vt + (size_t)(h * 64 + r) * 2048 + kb + cg * 8),
        (__attribute__((address_space(3))) void*)(&Vts[(w * 16 + i * 8) * 64]),
        16, 0, 0);
  }
  #pragma unroll
  for (int i = tid; i < N_TOK / SPLIT; i += 256)
    lball[i] = __builtin_amdgcn_logf(sz[kb + i]);   // v_log_f32 = log2
  __syncthreads();

  int cur = 0;
  for (int kt = kb; kt < ke; kt += 64) {
    const int nxt = cur ^ 1;
    const bool has_next = (kt + 64 < ke);

    if (has_next) {
      #pragma unroll
      for (int i = 0; i < 2; i++) {
        const int r = w * 16 + i * 8 + rl;
        __builtin_amdgcn_global_load_lds(
            (const __attribute__((address_space(1))) void*)(qkv + (size_t)(kt + 64 + r) * 3072 + 1024 + h * 64 + cg * 8),
            (__attribute__((address_space(3))) void*)(&Ks[nxt][(w * 16 + i * 8) * 64]),
            16, 0, 0);
      }
    }

    const u16* Kc = Ks[cur];
    f32x4 sacc[4] = {};
    #pragma unroll
    for (int kk = 0; kk < 2; kk++) {
      const int slot = (kk * 4 + quad) ^ (lane & 7);
      bf16x8 kf[4];
      #pragma unroll
      for (int jt = 0; jt < 4; jt++)
        kf[jt] = *(const bf16x8*)&Kc[(jt * 16 + col) * 64 + slot * 8];
      __builtin_amdgcn_s_setprio(1);
      #pragma unroll
      for (int jt = 0; jt < 4; jt++)
        sacc[jt] = __builtin_amdgcn_mfma_f32_16x16x32_bf16(kf[jt], qf[kk], sacc[jt], 0, 0, 0);
      __builtin_amdgcn_s_setprio(0);
    }

    u16* pw = Ps[w];
    const float* lbp = &lball[kt - kb];
    #pragma unroll
    for (int jt = 0; jt < 4; jt++) {
      float4 lb4 = *(const float4*)&lbp[jt * 16 + quad * 4];
      const float p0 = __builtin_amdgcn_exp2f(fmaf(sacc[jt][0], kScaleLog2e, lb4.x));
      const float p1 = __builtin_amdgcn_exp2f(fmaf(sacc[jt][1], kScaleLog2e, lb4.y));
      const float p2 = __builtin_amdgcn_exp2f(fmaf(sacc[jt][2], kScaleLog2e, lb4.z));
      const float p3 = __builtin_amdgcn_exp2f(fmaf(sacc[jt][3], kScaleLog2e, lb4.w));
      l_lane += (p0 + p1) + (p2 + p3);
      uint2 pkk;
      pkk.x = cvt_pk_bf16(p0, p1);
      pkk.y = cvt_pk_bf16(p2, p3);
      *(uint2*)&pw[col * 72 + jt * 16 + quad * 4] = pkk;
    }
    bf16x8 pf[2];
    #pragma unroll
    for (int kk = 0; kk < 2; kk++)
      pf[kk] = *(const bf16x8*)&pw[col * 72 + kk * 32 + quad * 8];

    __syncthreads();

    #pragma unroll
    for (int kk = 0; kk < 2; kk++) {
      const int slot = (kk * 4 + quad) ^ (lane & 7);
      bf16x8 vf[4];
      #pragma unroll
      for (int nt = 0; nt < 4; nt++)
        vf[nt] = *(const bf16x8*)&Vts[(nt * 16 + col) * 64 + slot * 8];
      __builtin_amdgcn_s_setprio(1);
      #pragma unroll
      for (int nt = 0; nt < 4; nt++)
        oacc[nt] = __builtin_amdgcn_mfma_f32_16x16x32_bf16(pf[kk], vf[nt], oacc[nt], 0, 0, 0);
      __builtin_amdgcn_s_setprio(0);
    }

    __syncthreads();

    if (has_next) {
      #pragma unroll
      for (int i = 0; i < 2; i++) {
        const int r = w * 16 + i * 8 + rl;
        __builtin_amdgcn_global_load_lds(
            (const __attribute__((address_space(1))) void*)(vt + (size_t)(h * 64 + r) * 2048 + kt + 64 + cg * 8),
            (__attribute__((address_space(3))) void*)(&Vts[(w * 16 + i * 8) * 64]),
            16, 0, 0);
      }
    }
    cur = nxt;
  }

  l_lane += __shfl_xor(l_lane, 16);
  l_lane += __shfl_xor(l_lane, 32);

  float* osl = opart + (size_t)blockIdx.z * ((size_t)N_TOK * 1024);
  #pragma unroll
  for (int r = 0; r < 4; r++) {
    const int q = q0 + w * 16 + quad * 4 + r;
    float* op = osl + (size_t)q * 1024 + h * 64 + col;
    #pragma unroll
    for (int nt = 0; nt < 4; nt++)
      op[nt * 16] = oacc[nt][r];
  }
  if (quad == 0)
    lpart[(size_t)blockIdx.z * (N_TOK * 16) + (q0 + w * 16 + col) * 16 + h] = l_lane;
}

// ------ fused attn-normalize + merge-score (independent work, packed) -----
__global__ __launch_bounds__(256) void norm_score_kernel(
    const float* __restrict__ opart, const float* __restrict__ lpart,
    u16* __restrict__ xa,
    const float* __restrict__ metric, const float* __restrict__ thr,
    int* __restrict__ mask, int* __restrict__ node)
{
  __shared__ float a[4][64];
  __shared__ float bw_[4][4];
  __shared__ int biw_[4][4];
  const int bid = blockIdx.x;
  const int t = threadIdx.x;
  if (bid < 2048) {
    const int q = bid;
    const int c = t * 4;
    float4 o0 = *(const float4*)(opart + (size_t)q * 1024 + c);
    float4 o1 = *(const float4*)(opart + (size_t)N_TOK * 1024 + (size_t)q * 1024 + c);
    const float l0 = lpart[q * 16 + (c >> 6)];
    const float l1 = lpart[N_TOK * 16 + q * 16 + (c >> 6)];
    const float inv = 1.0f / (l0 + l1);
    ushort4 o4;
    o4.x = f2bf((o0.x + o1.x) * inv); o4.y = f2bf((o0.y + o1.y) * inv);
    o4.z = f2bf((o0.z + o1.z) * inv); o4.w = f2bf((o0.w + o1.w) * inv);
    *(ushort4*)(xa + (size_t)q * 1024 + c) = o4;
    return;
  }
  const int s0 = (bid - 2048) * 4;
  a[t >> 6][t & 63] = metric[(size_t)(2 * (s0 + (t >> 6))) * 64 + (t & 63)];
  __syncthreads();
  float best[4] = {-INFINITY, -INFINITY, -INFINITY, -INFINITY};
  int besti[4] = {0, 0, 0, 0};
  for (int m = t; m < 1024; m += 256) {
    const float* bp = metric + (size_t)(2 * m + 1) * 64;
    float s[4] = {0.f, 0.f, 0.f, 0.f};
    #pragma unroll
    for (int d = 0; d < 64; d += 4) {
      float4 bv = *(const float4*)(bp + d);
      #pragma unroll
      for (int j = 0; j < 4; j++) {
        float4 av = *(const float4*)&a[j][d];
        s[j] += av.x*bv.x + av.y*bv.y + av.z*bv.z + av.w*bv.w;
      }
    }
    #pragma unroll
    for (int j = 0; j < 4; j++)
      if (s[j] > best[j]) { best[j] = s[j]; besti[j] = m; }   // ascending m
  }
  #pragma unroll
  for (int j = 0; j < 4; j++) {
    float b = best[j]; int bi = besti[j];
    #pragma unroll
    for (int off = 1; off < 64; off <<= 1) {
      float ov = __shfl_xor(b, off);
      int   oi = __shfl_xor(bi, off);
      if (ov > b || (ov == b && oi < bi)) { b = ov; bi = oi; }
    }
    best[j] = b; besti[j] = bi;
  }
  const int wv = t >> 6;
  if ((t & 63) == 0) {
    #pragma unroll
    for (int j = 0; j < 4; j++) { bw_[wv][j] = best[j]; biw_[wv][j] = besti[j]; }
  }
  __syncthreads();
  if (t < 4) {
    const int j = t;
    float b = bw_[0][j]; int bi = biw_[0][j];
    for (int ww = 1; ww < 4; ww++)
      if (bw_[ww][j] > b || (bw_[ww][j] == b && biw_[ww][j] < bi)) { b = bw_[ww][j]; bi = biw_[ww][j]; }
    const int n = s0 + j;
    if (n == 0) { mask[0] = 0; node[0] = 0; }
    else { mask[n] = (b > thr[0]) ? 1 : 0; node[n] = bi; }
  }
}

// ------ build merged rows; scan folded in (pos computed per-block) --------
__global__ __launch_bounds__(256) void build_kernel(
    const float* __restrict__ xres, const float* __restrict__ sz,
    const int* __restrict__ mask, float* __restrict__ xm,
    float* __restrict__ sizem, int U)
{
  const int b = blockIdx.x;
  const int t = threadIdx.x;
  __shared__ int red[4];
  int srow, orow;
  if (b < 1024) { srow = 2 * b + 1; orow = U + b; }
  else {
    const int i = b - 1024;
    if (mask[i]) return;
    int cnt = 0;
    for (int j = t; j < i; j += 256) cnt += mask[j] ? 0 : 1;
    #pragma unroll
    for (int off = 1; off < 64; off <<= 1) cnt += __shfl_xor(cnt, off);
    if ((t & 63) == 0) red[t >> 6] = cnt;
    __syncthreads();
    orow = red[0] + red[1] + red[2] + red[3];
    srow = 2 * i;
  }
  const float ssz = sz[srow];
  const float* xp = xres + (size_t)srow * 1024;
  float* op = xm + (size_t)orow * 1024;
  const int c = t * 4;
  float4 v = *(const float4*)(xp + c);
  v.x *= ssz; v.y *= ssz; v.z *= ssz; v.w *= ssz;
  *(float4*)(op + c) = v;
  if (t == 0) sizem[orow] = ssz;
}

// ---------------- scatter-add merged src tokens into dst rows -------------
__global__ __launch_bounds__(256) void merge_add_kernel(
    const float* __restrict__ xres, const float* __restrict__ sz,
    const int* __restrict__ mask, const int* __restrict__ node,
    float* __restrict__ xm, float* __restrict__ sizem, int U)
{
  const int i = blockIdx.x;
  if (!mask[i]) return;
  const int t = threadIdx.x;
  const int srow = 2 * i;
  const int orow = U + node[i];
  const float ssz = sz[srow];
  const float* xp = xres + (size_t)srow * 1024;
  float* op = xm + (size_t)orow * 1024;
  for (int c = t; c < 1024; c += 256)
    atomicAdd(op + c, xp[c] * ssz);
  if (t == 0) atomicAdd(sizem + orow, ssz);
}

extern "C" void kernel_launch(void* const* d_in, const int* in_sizes, int n_in,
                              void* d_out, int out_size, void* d_ws, size_t ws_size,
                              hipStream_t stream) {
  const float* x      = (const float*)d_in[0];
  const float* sz     = (const float*)d_in[1];
  const float* qkv_w  = (const float*)d_in[2];
  const float* proj_w = (const float*)d_in[3];
  const float* proj_b = (const float*)d_in[4];
  const float* ln1_g  = (const float*)d_in[5];
  const float* ln1_b  = (const float*)d_in[6];
  const float* ln2_g  = (const float*)d_in[7];
  const float* ln2_b  = (const float*)d_in[8];
  const float* fc1_w  = (const float*)d_in[9];
  const float* fc1_b  = (const float*)d_in[10];
  const float* fc2_w  = (const float*)d_in[11];
  const float* fc2_b  = (const float*)d_in[12];
  const float* thr    = (const float*)d_in[13];

  const int M = out_size / 1025;
  const int U = M - 1024;
  const size_t MB = 1u << 20;
  const size_t KB = 1u << 10;

  // workspace layout (ws = 256 MiB):
  //  [0,6)   w_qkvT          [6,7)   wbar/met/mask/node
  //  [7,7.25) lpart          [8,10)  w_projT
  //  [10,22) b_qkv -> b_xa[10,14) -> b_xm[10,18)
  //  [22,30) b_xres (fresh; b_hf DELETED — metric now LN-inline from x)
  //  [30,34) b_h (dead after QKV GEMM)
  //  [71,79) w_fc1T  [79,87) w_fc2T  [87,104) b_g
  //  [104,108) b_h2  [108,142) b_facc  [142,146) vt  [146,162) opart
  char* ws = (char*)d_ws;
  u16*   w_qkvT  = (u16*)(ws + 0);
  float* b_wbar  = (float*)(ws + 6 * MB);
  float* b_met   = (float*)(ws + 6 * MB + 256 * KB);
  int*   b_mask  = (int*)(ws + 6 * MB + 768 * KB);
  int*   b_node  = b_mask + 1024;
  float* b_szm   = (float*)(b_node + 1024);
  float* b_lpart = (float*)(ws + 7 * MB);            // 2 x 128KB slices
  u16*   w_projT = (u16*)(ws + 8 * MB);
  u16*   b_qkv   = (u16*)(ws + 10 * MB);
  u16*   b_xa    = (u16*)(ws + 10 * MB);   // over dead b_qkv (after attn)
  float* b_xm    = (float*)(ws + 10 * MB);   // over dead b_xa (after proj)
  float* b_xres  = (float*)(ws + 22 * MB);
  u16*   b_h     = (u16*)(ws + 30 * MB);
  u16*   w_fc1T  = (u16*)(ws + 71 * MB);
  u16*   w_fc2T  = (u16*)(ws + 79 * MB);
  u16*   b_g     = (u16*)(ws + 87 * MB);
  u16*   b_h2    = (u16*)(ws + 104 * MB);
  float* b_facc  = (float*)(ws + 108 * MB);  // 4 partitioned slices
  u16*   b_vt    = (u16*)(ws + 142 * MB);    // written by QKV GEMM
  float* b_opart = (float*)(ws + 146 * MB);  // 2 x 8MB slices

  float* outx = (float*)d_out;
  float* outs = outx + (size_t)M * 1024;

  // 1. tiny wbar launch (must precede fused_pre: its metric blocks read it)
  wbar_kernel<<<256, 256, 0, stream>>>(qkv_w, b_wbar);
  // 2. fused opening launch: metric(inline-LN, scheduled first) + LN1 +
  //    ALL weight converts — metric's 15us VALU chain shadows the
  //    memory-bound streaming blocks
  fused_pre_kernel<<<14848, 256, 0, stream>>>(
      x, ln1_g, ln1_b, b_h,
      qkv_w, w_qkvT, proj_w, w_projT, fc1_w, w_fc1T, fc2_w, w_fc2T,
      b_wbar, b_met);
  // 3. pure QKV GEMM; V-third blocks store TRANSPOSED into b_vt
  gemm_mfma<128, 64, 1, false, false, false, true, true><<<dim3(48, 16), 256, 0, stream>>>(
      b_h, w_qkvT, nullptr, (const float*)b_vt, b_qkv, 2048, 3072, 1024);
  // 4. pure MFMA attention (R12-proven form)
  attn_mfma<2><<<dim3(32, 16, 2), 256, 0, stream>>>(b_qkv, b_vt, sz, b_opart, b_lpart);
  // 5. fused attn-normalize + merge-score (independent, packed)
  norm_score_kernel<<<2304, 256, 0, stream>>>(b_opart, b_lpart, b_xa, b_met, thr, b_mask, b_node);
  // 6. proj GEMM + bias + residual(x) -> xres fp32 — 512 blocks
  gemm_mfma<64, 64, 1, true, false, true, false><<<dim3(16, 32), 256, 0, stream>>>(
      b_xa, w_projT, proj_b, x, b_xres, 2048, 1024, 1024);
  // 7. build merged rows (scan folded in)
  build_kernel<<<2048, 256, 0, stream>>>(b_xres, sz, b_mask, b_xm, b_szm, U);
  // 8. scatter-add merged src tokens
  merge_add_kernel<<<1024, 256, 0, stream>>>(b_xres, sz, b_mask, b_node, b_xm, b_szm, U);
  // 9. fused divide + LN2 (one block per row): outx, outs, h2
  divide_ln2_kernel<<<M, 256, 0, stream>>>(b_xm, b_szm, ln2_g, ln2_b, outx, outs, b_h2);
  // 10. fc1 + bias + exact GELU -> bf16 — 768 blocks
  gemm_mfma<128, 64, 1, true, true, false, true><<<dim3(64, (M + 127) / 128), 256, 0, stream>>>(
      b_h2, w_fc1T, fc1_b, nullptr, b_g, M, 4096, 1024);
  // 11. fc2 split-K=4, partitioned slices (no memset, no atomics)
  gemm_mfma<128, 64, 4, false, false, false, false><<<dim3(16, (M + 127) / 128, 4), 256, 0, stream>>>(
      b_g, w_fc2T, nullptr, nullptr, b_facc, M, 1024, 4096);
  // 12. fc2 epilogue: outx += sum(4 slices) + bias (residual in-place)
  splitk_epilogue_kernel<<<(M * 256 + 255) / 256, 256, 0, stream>>>(
      b_facc, fc2_b, outx, M);
  (void)in_sizes; (void)n_in; (void)ws_size;
}

// Round 17
// 282.431 us; speedup vs baseline: 1.0040x; 1.0040x over previous
//
#include <hip/hip_runtime.h>
#include <math.h>

typedef unsigned short u16;
typedef __attribute__((ext_vector_type(8))) short bf16x8;
typedef __attribute__((ext_vector_type(4))) float f32x4;

#define C_DIM 1024
#define N_TOK 2048

static __device__ __forceinline__ u16 f2bf(float f) {
  union { float f; unsigned u; } v; v.f = f;
  unsigned r = v.u + 0x7fff + ((v.u >> 16) & 1);
  return (u16)(r >> 16);
}

// packed f32x2 -> bf16x2 (RNE, same rounding as f2bf) in ONE VALU op
static __device__ __forceinline__ unsigned cvt_pk_bf16(float lo, float hi) {
  unsigned r;
  asm("v_cvt_pk_bf16_f32 %0, %1, %2" : "=v"(r) : "v"(lo), "v"(hi));
  return r;
}

// ---------------- wbar[c][d] = mean over heads of k-weights ---------------
__global__ __launch_bounds__(256) void wbar_kernel(
    const float* __restrict__ qkv_w, float* __restrict__ wbar)
{
  const int idx = blockIdx.x * 256 + threadIdx.x;   // c*64 + d
  const int c = idx >> 6, d = idx & 63;
  float s = 0.f;
  #pragma unroll
  for (int h = 0; h < 16; h++)
    s += qkv_w[(size_t)c * 3072 + 1024 + h * 64 + d];
  wbar[idx] = s * (1.0f / 16.0f);
}

// ---------------- transpose body: W[K][N] tile (by,bx) -> WT[N][K] --------
static __device__ __forceinline__ void conv_body(
    const float* __restrict__ W, u16* __restrict__ WT, int K, int N,
    int bx, int by, float (*tile)[33], int tx, int ty)
{
  #pragma unroll
  for (int i = 0; i < 32; i += 8)
    tile[ty + i][tx] = W[(size_t)(by + ty + i) * N + bx + tx];
  __syncthreads();
  #pragma unroll
  for (int i = 0; i < 32; i += 8)
    WT[(size_t)(bx + ty + i) * K + by + tx] = f2bf(tile[tx][ty + i]);
}

// ---- fused opening launch: METRIC(inline LN1) + LN1 + ALL weight converts
__global__ __launch_bounds__(256) void fused_pre_kernel(
    const float* __restrict__ x, const float* __restrict__ ln1_g,
    const float* __restrict__ ln1_b, u16* __restrict__ b_h,
    const float* __restrict__ qkv_w, u16* __restrict__ w_qkvT,
    const float* __restrict__ proj_w, u16* __restrict__ w_projT,
    const float* __restrict__ fc1_w, u16* __restrict__ w_fc1T,
    const float* __restrict__ fc2_w, u16* __restrict__ w_fc2T,
    const float* __restrict__ wbar, float* __restrict__ metric)
{
  __shared__ __attribute__((aligned(16))) char smem[16384];
  __shared__ float rs[4], rss[4];
  const int bid = blockIdx.x;
  const int t = threadIdx.x;

  if (bid < 512) {           // ---- metric with inline LN1 (fp32) ----
    float (*hs)[1024] = (float(*)[1024])smem;
    const int w = t >> 6;
    const int lane = t & 63;
    const int n0 = bid * 4;
    const float* xr = x + (size_t)(n0 + w) * C_DIM;
    float4 xv0 = *(const float4*)(xr + lane * 4);
    float4 xv1 = *(const float4*)(xr + 256 + lane * 4);
    float4 xv2 = *(const float4*)(xr + 512 + lane * 4);
    float4 xv3 = *(const float4*)(xr + 768 + lane * 4);
    float s  = (xv0.x + xv0.y + xv0.z + xv0.w) + (xv1.x + xv1.y + xv1.z + xv1.w)
             + (xv2.x + xv2.y + xv2.z + xv2.w) + (xv3.x + xv3.y + xv3.z + xv3.w);
    float ss = (xv0.x*xv0.x + xv0.y*xv0.y + xv0.z*xv0.z + xv0.w*xv0.w)
             + (xv1.x*xv1.x + xv1.y*xv1.y + xv1.z*xv1.z + xv1.w*xv1.w)
             + (xv2.x*xv2.x + xv2.y*xv2.y + xv2.z*xv2.z + xv2.w*xv2.w)
             + (xv3.x*xv3.x + xv3.y*xv3.y + xv3.z*xv3.z + xv3.w*xv3.w);
    #pragma unroll
    for (int off = 1; off < 64; off <<= 1) {
      s  += __shfl_xor(s, off);
      ss += __shfl_xor(ss, off);
    }
    const float mean = s * (1.0f / C_DIM);
    const float var  = ss * (1.0f / C_DIM) - mean * mean;
    const float inv  = rsqrtf(var + 1e-5f);
    #pragma unroll
    for (int k = 0; k < 4; k++) {
      const float4 xv = (k == 0) ? xv0 : (k == 1) ? xv1 : (k == 2) ? xv2 : xv3;
      float4 gv = *(const float4*)(ln1_g + k * 256 + lane * 4);
      float4 bv = *(const float4*)(ln1_b + k * 256 + lane * 4);
      float4 o;
      o.x = (xv.x - mean) * inv * gv.x + bv.x;
      o.y = (xv.y - mean) * inv * gv.y + bv.y;
      o.z = (xv.z - mean) * inv * gv.z + bv.z;
      o.w = (xv.w - mean) * inv * gv.w + bv.w;
      *(float4*)&hs[w][k * 256 + lane * 4] = o;
    }
    __syncthreads();
    const int d = t & 63;
    const float* hsw = hs[t >> 6];
    float a0=0,a1=0,a2=0,a3=0,a4=0,a5=0,a6=0,a7=0;
    for (int c = 0; c < 1024; c += 8) {
      a0 += hsw[c+0] * wbar[(c+0)*64 + d];
      a1 += hsw[c+1] * wbar[(c+1)*64 + d];
      a2 += hsw[c+2] * wbar[(c+2)*64 + d];
      a3 += hsw[c+3] * wbar[(c+3)*64 + d];
      a4 += hsw[c+4] * wbar[(c+4)*64 + d];
      a5 += hsw[c+5] * wbar[(c+5)*64 + d];
      a6 += hsw[c+6] * wbar[(c+6)*64 + d];
      a7 += hsw[c+7] * wbar[(c+7)*64 + d];
    }
    float sm = ((a0+a1)+(a2+a3)) + ((a4+a5)+(a6+a7));
    float sq = sm * sm;
    #pragma unroll
    for (int off = 1; off < 64; off <<= 1) sq += __shfl_xor(sq, off);
    metric[(size_t)(n0 + (t >> 6)) * 64 + d] = sm / sqrtf(sq);
    return;
  }

  const int tx = t & 31, ty = t >> 5;
  float (*tile)[33] = (float(*)[33])smem;
  if (bid < 2560) {            // ---- LN1 -> bf16 (verbatim reduction) ----
    const int row = bid - 512;
    const float* xr = x + (size_t)row * C_DIM;
    float4 xv = *(const float4*)(xr + t * 4);
    float s  = xv.x + xv.y + xv.z + xv.w;
    float ss = xv.x*xv.x + xv.y*xv.y + xv.z*xv.z + xv.w*xv.w;
    #pragma unroll
    for (int off = 1; off < 64; off <<= 1) {
      s  += __shfl_xor(s, off);
      ss += __shfl_xor(ss, off);
    }
    const int w = t >> 6;
    if ((t & 63) == 0) { rs[w] = s; rss[w] = ss; }
    __syncthreads();
    s  = rs[0] + rs[1] + rs[2] + rs[3];
    ss = rss[0] + rss[1] + rss[2] + rss[3];
    const float mean = s * (1.0f / C_DIM);
    const float var  = ss * (1.0f / C_DIM) - mean * mean;
    const float inv  = rsqrtf(var + 1e-5f);
    float4 gv = *(const float4*)(ln1_g + t * 4);
    float4 bv = *(const float4*)(ln1_b + t * 4);
    float4 o;
    o.x = (xv.x - mean) * inv * gv.x + bv.x;
    o.y = (xv.y - mean) * inv * gv.y + bv.y;
    o.z = (xv.z - mean) * inv * gv.z + bv.z;
    o.w = (xv.w - mean) * inv * gv.w + bv.w;
    ushort4 o4;
    o4.x = f2bf(o.x); o4.y = f2bf(o.y); o4.z = f2bf(o.z); o4.w = f2bf(o.w);
    *(ushort4*)(b_h + (size_t)row * C_DIM + t * 4) = o4;
  } else if (bid < 5632) {     // ---- qkv^T: 96 x 32 tiles ----
    const int b2 = bid - 2560;
    conv_body(qkv_w, w_qkvT, 1024, 3072, (b2 % 96) * 32, (b2 / 96) * 32, tile, tx, ty);
  } else if (bid < 6656) {     // ---- proj^T: 32 x 32 tiles ----
    const int b2 = bid - 5632;
    conv_body(proj_w, w_projT, 1024, 1024, (b2 % 32) * 32, (b2 / 32) * 32, tile, tx, ty);
  } else if (bid < 10752) {    // ---- fc1^T: 128 x 32 tiles ----
    const int b2 = bid - 6656;
    conv_body(fc1_w, w_fc1T, 1024, 4096, (b2 % 128) * 32, (b2 / 128) * 32, tile, tx, ty);
  } else {                     // ---- fc2^T: 32 x 128 tiles ----
    const int b2 = bid - 10752;
    conv_body(fc2_w, w_fc2T, 4096, 1024, (b2 % 32) * 32, (b2 / 32) * 32, tile, tx, ty);
  }
}

// -------- fused divide + LN2: v = xm/size -> outx/outs, LN(v) -> h2 -------
__global__ __launch_bounds__(256) void divide_ln2_kernel(
    const float* __restrict__ xm, const float* __restrict__ sizem,
    const float* __restrict__ g, const float* __restrict__ b,
    float* __restrict__ outx, float* __restrict__ outs,
    u16* __restrict__ h2)
{
  const int row = blockIdx.x;
  const int t = threadIdx.x;
  const float sz = sizem[row];
  float4 xv = *(const float4*)(xm + (size_t)row * C_DIM + t * 4);
  xv.x = xv.x / sz; xv.y = xv.y / sz; xv.z = xv.z / sz; xv.w = xv.w / sz;
  *(float4*)(outx + (size_t)row * C_DIM + t * 4) = xv;
  if (t == 0) outs[row] = sz;
  float s  = xv.x + xv.y + xv.z + xv.w;
  float ss = xv.x*xv.x + xv.y*xv.y + xv.z*xv.z + xv.w*xv.w;
  #pragma unroll
  for (int off = 1; off < 64; off <<= 1) {
    s  += __shfl_xor(s, off);
    ss += __shfl_xor(ss, off);
  }
  __shared__ float rs[4], rss[4];
  const int w = t >> 6;
  if ((t & 63) == 0) { rs[w] = s; rss[w] = ss; }
  __syncthreads();
  s  = rs[0] + rs[1] + rs[2] + rs[3];
  ss = rss[0] + rss[1] + rss[2] + rss[3];
  const float mean = s * (1.0f / C_DIM);
  const float var  = ss * (1.0f / C_DIM) - mean * mean;
  const float inv  = rsqrtf(var + 1e-5f);
  float4 gv = *(const float4*)(g + t * 4);
  float4 bv = *(const float4*)(b + t * 4);
  float4 o;
  o.x = (xv.x - mean) * inv * gv.x + bv.x;
  o.y = (xv.y - mean) * inv * gv.y + bv.y;
  o.z = (xv.z - mean) * inv * gv.z + bv.z;
  o.w = (xv.w - mean) * inv * gv.w + bv.w;
  ushort4 o4;
  o4.x = f2bf(o.x); o4.y = f2bf(o.y); o4.z = f2bf(o.z); o4.w = f2bf(o.w);
  *(ushort4*)(h2 + (size_t)row * C_DIM + t * 4) = o4;
}

// ---------------- bf16 MFMA GEMM: C[M,N] = A[M,K] @ BT[N,K]^T -------------
// R6 geometry (proven): BN=64, LDS double-buffer, one barrier/iter.
// SPLIT>1: partitioned slices. VTOUT (R14-verified): blocks with bn>=2048
// (V-third of QKV GEMM) store the C-tile TRANSPOSED to vt[d][token].
template<int BM, int BN, int SPLIT, bool BIAS, bool GELU, bool RES, bool OUT_BF16, bool VTOUT = false>
__global__ __launch_bounds__(256) void gemm_mfma(
    const u16* __restrict__ A,   // [>=gridDim.y*BM][K] bf16 (readable padding)
    const u16* __restrict__ BT,  // [N][K] bf16
    const float* __restrict__ bias, const float* __restrict__ res,
    void* __restrict__ Cout, int M, int N, int K)
{
  constexpr int TM = BM / 32;                 // 16x16 tiles per wave (rows)
  constexpr int TN = BN / 32;                 // 16x16 tiles per wave (cols)
  __shared__ u16 As[2][BM * 64] __attribute__((aligned(16)));
  __shared__ u16 Bs[2][BN * 64] __attribute__((aligned(16)));
  const int tid  = threadIdx.x;
  const int lane = tid & 63;
  const int w    = tid >> 6;
  const int bm = blockIdx.y * BM;
  const int bn = blockIdx.x * BN;
  const int wm = (w >> 1) * (BM / 2);
  const int wn = (w & 1) * (BN / 2);

  f32x4 acc[TM][TN] = {};

  const int rl = lane >> 3;                 // row-in-8-group
  const int cg = (lane & 7) ^ rl;           // swizzled source chunk

  const int kb = (K / SPLIT) * blockIdx.z;
  const int ke = kb + K / SPLIT;

#define GEMM_STAGE(buf, k0_)                                                   \
  {                                                                            \
    _Pragma("unroll")                                                          \
    for (int i = 0; i < BM / 32; i++) {                                        \
      const int r = w * (BM / 4) + i * 8 + rl;                                 \
      __builtin_amdgcn_global_load_lds(                                        \
          (const __attribute__((address_space(1))) void*)(A + (size_t)(bm + r) * K + (k0_) + cg * 8), \
          (__attribute__((address_space(3))) void*)(&As[buf][(w * (BM / 4) + i * 8) * 64]), \
          16, 0, 0);                                                           \
    }                                                                          \
    _Pragma("unroll")                                                          \
    for (int i = 0; i < BN / 32; i++) {                                        \
      const int r = w * (BN / 4) + i * 8 + rl;                                 \
      __builtin_amdgcn_global_load_lds(                                        \
          (const __attribute__((address_space(1))) void*)(BT + (size_t)(bn + r) * K + (k0_) + cg * 8), \
          (__attribute__((address_space(3))) void*)(&Bs[buf][(w * (BN / 4) + i * 8) * 64]), \
          16, 0, 0);                                                           \
    }                                                                          \
  }

  // prologue: stage first K-tile into buffer 0
  GEMM_STAGE(0, kb);
  __syncthreads();

  int cur = 0;
  for (int k0 = kb; k0 < ke; k0 += 64) {
    // issue next tile's loads into the other buffer (overlap compute)
    if (k0 + 64 < ke) GEMM_STAGE(cur ^ 1, k0 + 64);

    #pragma unroll
    for (int kk = 0; kk < 2; kk++) {
      bf16x8 af[TM], bfr[TN];
      const int slot = (kk * 4 + (lane >> 4)) ^ (lane & 7);
      #pragma unroll
      for (int i = 0; i < TM; i++)
        af[i] = *(const bf16x8*)&As[cur][(wm + i * 16 + (lane & 15)) * 64 + slot * 8];
      #pragma unroll
      for (int j = 0; j < TN; j++)
        bfr[j] = *(const bf16x8*)&Bs[cur][(wn + j * 16 + (lane & 15)) * 64 + slot * 8];
      __builtin_amdgcn_s_setprio(1);
      #pragma unroll
      for (int i = 0; i < TM; i++)
        #pragma unroll
        for (int j = 0; j < TN; j++)
          acc[i][j] = __builtin_amdgcn_mfma_f32_16x16x32_bf16(af[i], bfr[j], acc[i][j], 0, 0, 0);
      __builtin_amdgcn_s_setprio(0);
    }
    __syncthreads();
    cur ^= 1;
  }
#undef GEMM_STAGE

  if constexpr (VTOUT) {
    if (bn >= 2048) {
      // transposed V store: tile[n_local][m_local], stride 132 u16
      u16* tile = (u16*)&As[0][0];
      #pragma unroll
      for (int i = 0; i < TM; i++)
        #pragma unroll
        for (int j = 0; j < TN; j++) {
          const int nl = wn + j * 16 + (lane & 15);
          const int mb = wm + i * 16 + (lane >> 4) * 4;
          uint2 pk;
          pk.x = cvt_pk_bf16(acc[i][j][0], acc[i][j][1]);
          pk.y = cvt_pk_bf16(acc[i][j][2], acc[i][j][3]);
          *(uint2*)&tile[nl * 132 + mb] = pk;
        }
      __syncthreads();
      u16* vt = (u16*)res;               // vt base smuggled via res
      const int row = tid >> 2;          // 0..63  (n_local)
      const int cc  = (tid & 3) * 32;    // m chunk
      #pragma unroll
      for (int c4 = 0; c4 < 8; c4++) {
        ushort4 v4 = *(const ushort4*)&tile[row * 132 + cc + c4 * 4];
        *(ushort4*)&vt[(size_t)(bn - 2048 + row) * 2048 + bm + cc + c4 * 4] = v4;
      }
      return;
    }
  }

  if constexpr (SPLIT > 1) {
    // partitioned plain stores: slice z at Cf + z*M*N (sole writer)
    float* Cf = (float*)Cout + (size_t)blockIdx.z * ((size_t)M * N);
    #pragma unroll
    for (int i = 0; i < TM; i++)
      #pragma unroll
      for (int r = 0; r < 4; r++) {
        const int m = bm + wm + i * 16 + (lane >> 4) * 4 + r;
        if (m < M) {
          #pragma unroll
          for (int j = 0; j < TN; j++) {
            const int n = bn + wn + j * 16 + (lane & 15);
            Cf[(size_t)m * N + n] = acc[i][j][r];
          }
        }
      }
  } else {
    #pragma unroll
    for (int i = 0; i < TM; i++) {
      #pragma unroll
      for (int r = 0; r < 4; r++) {
        const int m = bm + wm + i * 16 + (lane >> 4) * 4 + r;
        if (m < M) {
          #pragma unroll
          for (int j = 0; j < TN; j++) {
            const int n = bn + wn + j * 16 + (lane & 15);
            float v = acc[i][j][r];
            if (BIAS) v += bias[n];
            if (GELU) v = 0.5f * v * (1.0f + erff(v * 0.70710678118654752f));
            if (RES)  v += res[(size_t)m * N + n];
            if (OUT_BF16) ((u16*)Cout)[(size_t)m * N + n] = f2bf(v);
            else          ((float*)Cout)[(size_t)m * N + n] = v;
          }
        }
      }
    }
  }
}

// ------ split-K epilogue: out += sum(4 slices) + bias (in-place res) ------
__global__ __launch_bounds__(256) void splitk_epilogue_kernel(
    const float* __restrict__ acc, const float* __restrict__ bias,
    float* __restrict__ out, int M)
{
  const int idx = blockIdx.x * 256 + threadIdx.x;   // float4 index
  if (idx >= M * 256) return;
  const size_t S = (size_t)M * 256;                 // slice stride in float4
  const float4* a4 = (const float4*)acc;
  float4 a0 = a4[idx], a1 = a4[idx + S], a2 = a4[idx + 2 * S], a3 = a4[idx + 3 * S];
  float4 bv = *(const float4*)(bias + (idx & 255) * 4);
  float4 o = *(const float4*)(out + (size_t)idx * 4);
  o.x += (a0.x + a1.x) + (a2.x + a3.x) + bv.x;
  o.y += (a0.y + a1.y) + (a2.y + a3.y) + bv.y;
  o.z += (a0.z + a1.z) + (a2.z + a3.z) + bv.z;
  o.w += (a0.w + a1.w) + (a2.w + a3.w) + bv.w;
  *(float4*)(out + (size_t)idx * 4) = o;
}

// ---------------- MFMA flash attention (XCD-localized K/V sharing) --------
// R16: flattened 1D grid with XCD-aware swizzle. The 32 blocks sharing one
// (h,z) K/V panel (~1MB) previously round-robined across all 8 XCDs -> each
// XCD's 4MB L2 pulled nearly the whole 8MB KV set (FETCH 34.9MB vs ~12MB
// ideal). Decode L: xcd=L&7, j=L>>3, combo=xcd*4+(j>>5), qx=j&31 — each XCD
// owns 4 complete (h,z) combos (bijective remap; dispatch round-robin
// heuristic per guide §1, speed-only).
template<int SPLIT>
__global__ __launch_bounds__(256) void attn_mfma(
    const u16* __restrict__ qkv, const u16* __restrict__ vt,
    const float* __restrict__ sz, float* __restrict__ opart,
    float* __restrict__ lpart)
{
  const int L = blockIdx.x;
  const int xcd = L & 7;
  const int j = L >> 3;                       // 0..127
  const int combo = xcd * 4 + (j >> 5);       // 0..31
  const int qx = j & 31;
  const int h = combo & 15;
  const int z = combo >> 4;                   // 0..SPLIT-1 (SPLIT=2)

  const int q0  = qx * 64;
  const int tid = threadIdx.x;
  const int lane = tid & 63;
  const int w    = tid >> 6;
  const int col  = lane & 15;
  const int quad = lane >> 4;

  __shared__ u16 Ks [2][64 * 64] __attribute__((aligned(16)));
  __shared__ u16 Vts[64 * 64] __attribute__((aligned(16)));
  __shared__ u16 Ps[4][16 * 72] __attribute__((aligned(16)));
  __shared__ float lball[N_TOK / SPLIT];

  bf16x8 qf[2];
  {
    const u16* qp = qkv + (size_t)(q0 + w * 16 + col) * 3072 + h * 64 + quad * 8;
    qf[0] = *(const bf16x8*)(qp);
    qf[1] = *(const bf16x8*)(qp + 32);
  }

  float l_lane = 0.f;
  f32x4 oacc[4] = {};

  const int rl = lane >> 3;
  const int cg = (lane & 7) ^ rl;
  const int kb = z * (N_TOK / SPLIT);
  const int ke = kb + N_TOK / SPLIT;

  constexpr float kScaleLog2e = 0.18033688011112042f;  // 0.125*log2(e)

  #pragma unroll
  for (int i = 0; i < 2; i++) {
    const int r = w * 16 + i * 8 + rl;
    __builtin_amdgcn_global_load_lds(
        (const __attribute__((address_space(1))) void*)(qkv + (size_t)(kb + r) * 3072 + 1024 + h * 64 + cg * 8),
        (__attribute__((address_space(3))) void*)(&Ks[0][(w * 16 + i * 8) * 64]),
        16, 0, 0);
    __builtin_amdgcn_global_load_lds(
        (const __attribute__((address_space(1))) void*)(vt + (size_t)(h * 64 + r) * 2048 + kb + cg * 8),
        (__attribute__((address_space(3))) void*)(&Vts[(w * 16 + i * 8) * 64]),
        16, 0, 0);
  }
  #pragma unroll
  for (int i = tid; i < N_TOK / SPLIT; i += 256)
    lball[i] = __builtin_amdgcn_logf(sz[kb + i]);   // v_log_f32 = log2
  __syncthreads();

  int cur = 0;
  for (int kt = kb; kt < ke; kt += 64) {
    const int nxt = cur ^ 1;
    const bool has_next = (kt + 64 < ke);

    if (has_next) {
      #pragma unroll
      for (int i = 0; i < 2; i++) {
        const int r = w * 16 + i * 8 + rl;
        __builtin_amdgcn_global_load_lds(
            (const __attribute__((address_space(1))) void*)(qkv + (size_t)(kt + 64 + r) * 3072 + 1024 + h * 64 + cg * 8),
            (__attribute__((address_space(3))) void*)(&Ks[nxt][(w * 16 + i * 8) * 64]),
            16, 0, 0);
      }
    }

    const u16* Kc = Ks[cur];
    f32x4 sacc[4] = {};
    #pragma unroll
    for (int kk = 0; kk < 2; kk++) {
      const int slot = (kk * 4 + quad) ^ (lane & 7);
      bf16x8 kf[4];
      #pragma unroll
      for (int jt = 0; jt < 4; jt++)
        kf[jt] = *(const bf16x8*)&Kc[(jt * 16 + col) * 64 + slot * 8];
      __builtin_amdgcn_s_setprio(1);
      #pragma unroll
      for (int jt = 0; jt < 4; jt++)
        sacc[jt] = __builtin_amdgcn_mfma_f32_16x16x32_bf16(kf[jt], qf[kk], sacc[jt], 0, 0, 0);
      __builtin_amdgcn_s_setprio(0);
    }

    u16* pw = Ps[w];
    const float* lbp = &lball[kt - kb];
    #pragma unroll
    for (int jt = 0; jt < 4; jt++) {
      float4 lb4 = *(const float4*)&lbp[jt * 16 + quad * 4];
      const float p0 = __builtin_amdgcn_exp2f(fmaf(sacc[jt][0], kScaleLog2e, lb4.x));
      const float p1 = __builtin_amdgcn_exp2f(fmaf(sacc[jt][1], kScaleLog2e, lb4.y));
      const float p2 = __builtin_amdgcn_exp2f(fmaf(sacc[jt][2], kScaleLog2e, lb4.z));
      const float p3 = __builtin_amdgcn_exp2f(fmaf(sacc[jt][3], kScaleLog2e, lb4.w));
      l_lane += (p0 + p1) + (p2 + p3);
      uint2 pkk;
      pkk.x = cvt_pk_bf16(p0, p1);
      pkk.y = cvt_pk_bf16(p2, p3);
      *(uint2*)&pw[col * 72 + jt * 16 + quad * 4] = pkk;
    }
    bf16x8 pf[2];
    #pragma unroll
    for (int kk = 0; kk < 2; kk++)
      pf[kk] = *(const bf16x8*)&pw[col * 72 + kk * 32 + quad * 8];

    __syncthreads();

    #pragma unroll
    for (int kk = 0; kk < 2; kk++) {
      const int slot = (kk * 4 + quad) ^ (lane & 7);
      bf16x8 vf[4];
      #pragma unroll
      for (int nt = 0; nt < 4; nt++)
        vf[nt] = *(const bf16x8*)&Vts[(nt * 16 + col) * 64 + slot * 8];
      __builtin_amdgcn_s_setprio(1);
      #pragma unroll
      for (int nt = 0; nt < 4; nt++)
        oacc[nt] = __builtin_amdgcn_mfma_f32_16x16x32_bf16(pf[kk], vf[nt], oacc[nt], 0, 0, 0);
      __builtin_amdgcn_s_setprio(0);
    }

    __syncthreads();

    if (has_next) {
      #pragma unroll
      for (int i = 0; i < 2; i++) {
        const int r = w * 16 + i * 8 + rl;
        __builtin_amdgcn_global_load_lds(
            (const __attribute__((address_space(1))) void*)(vt + (size_t)(h * 64 + r) * 2048 + kt + 64 + cg * 8),
            (__attribute__((address_space(3))) void*)(&Vts[(w * 16 + i * 8) * 64]),
            16, 0, 0);
      }
    }
    cur = nxt;
  }

  l_lane += __shfl_xor(l_lane, 16);
  l_lane += __shfl_xor(l_lane, 32);

  float* osl = opart + (size_t)z * ((size_t)N_TOK * 1024);
  #pragma unroll
  for (int r = 0; r < 4; r++) {
    const int q = q0 + w * 16 + quad * 4 + r;
    float* op = osl + (size_t)q * 1024 + h * 64 + col;
    #pragma unroll
    for (int nt = 0; nt < 4; nt++)
      op[nt * 16] = oacc[nt][r];
  }
  if (quad == 0)
    lpart[(size_t)z * (N_TOK * 16) + (q0 + w * 16 + col) * 16 + h] = l_lane;
}

// ------ fused attn-normalize + merge-score (independent work, packed) -----
__global__ __launch_bounds__(256) void norm_score_kernel(
    const float* __restrict__ opart, const float* __restrict__ lpart,
    u16* __restrict__ xa,
    const float* __restrict__ metric, const float* __restrict__ thr,
    int* __restrict__ mask, int* __restrict__ node)
{
  __shared__ float a[4][64];
  __shared__ float bw_[4][4];
  __shared__ int biw_[4][4];
  const int bid = blockIdx.x;
  const int t = threadIdx.x;
  if (bid < 2048) {
    const int q = bid;
    const int c = t * 4;
    float4 o0 = *(const float4*)(opart + (size_t)q * 1024 + c);
    float4 o1 = *(const float4*)(opart + (size_t)N_TOK * 1024 + (size_t)q * 1024 + c);
    const float l0 = lpart[q * 16 + (c >> 6)];
    const float l1 = lpart[N_TOK * 16 + q * 16 + (c >> 6)];
    const float inv = 1.0f / (l0 + l1);
    ushort4 o4;
    o4.x = f2bf((o0.x + o1.x) * inv); o4.y = f2bf((o0.y + o1.y) * inv);
    o4.z = f2bf((o0.z + o1.z) * inv); o4.w = f2bf((o0.w + o1.w) * inv);
    *(ushort4*)(xa + (size_t)q * 1024 + c) = o4;
    return;
  }
  const int s0 = (bid - 2048) * 4;
  a[t >> 6][t & 63] = metric[(size_t)(2 * (s0 + (t >> 6))) * 64 + (t & 63)];
  __syncthreads();
  float best[4] = {-INFINITY, -INFINITY, -INFINITY, -INFINITY};
  int besti[4] = {0, 0, 0, 0};
  for (int m = t; m < 1024; m += 256) {
    const float* bp = metric + (size_t)(2 * m + 1) * 64;
    float s[4] = {0.f, 0.f, 0.f, 0.f};
    #pragma unroll
    for (int d = 0; d < 64; d += 4) {
      float4 bv = *(const float4*)(bp + d);
      #pragma unroll
      for (int j = 0; j < 4; j++) {
        float4 av = *(const float4*)&a[j][d];
        s[j] += av.x*bv.x + av.y*bv.y + av.z*bv.z + av.w*bv.w;
      }
    }
    #pragma unroll
    for (int j = 0; j < 4; j++)
      if (s[j] > best[j]) { best[j] = s[j]; besti[j] = m; }   // ascending m
  }
  #pragma unroll
  for (int j = 0; j < 4; j++) {
    float b = best[j]; int bi = besti[j];
    #pragma unroll
    for (int off = 1; off < 64; off <<= 1) {
      float ov = __shfl_xor(b, off);
      int   oi = __shfl_xor(bi, off);
      if (ov > b || (ov == b && oi < bi)) { b = ov; bi = oi; }
    }
    best[j] = b; besti[j] = bi;
  }
  const int wv = t >> 6;
  if ((t & 63) == 0) {
    #pragma unroll
    for (int j = 0; j < 4; j++) { bw_[wv][j] = best[j]; biw_[wv][j] = besti[j]; }
  }
  __syncthreads();
  if (t < 4) {
    const int j = t;
    float b = bw_[0][j]; int bi = biw_[0][j];
    for (int ww = 1; ww < 4; ww++)
      if (bw_[ww][j] > b || (bw_[ww][j] == b && biw_[ww][j] < bi)) { b = bw_[ww][j]; bi = biw_[ww][j]; }
    const int n = s0 + j;
    if (n == 0) { mask[0] = 0; node[0] = 0; }
    else { mask[n] = (b > thr[0]) ? 1 : 0; node[n] = bi; }
  }
}

// ------ build merged rows; scan folded in (pos computed per-block) --------
__global__ __launch_bounds__(256) void build_kernel(
    const float* __restrict__ xres, const float* __restrict__ sz,
    const int* __restrict__ mask, float* __restrict__ xm,
    float* __restrict__ sizem, int U)
{
  const int b = blockIdx.x;
  const int t = threadIdx.x;
  __shared__ int red[4];
  int srow, orow;
  if (b < 1024) { srow = 2 * b + 1; orow = U + b; }
  else {
    const int i = b - 1024;
    if (mask[i]) return;
    int cnt = 0;
    for (int j = t; j < i; j += 256) cnt += mask[j] ? 0 : 1;
    #pragma unroll
    for (int off = 1; off < 64; off <<= 1) cnt += __shfl_xor(cnt, off);
    if ((t & 63) == 0) red[t >> 6] = cnt;
    __syncthreads();
    orow = red[0] + red[1] + red[2] + red[3];
    srow = 2 * i;
  }
  const float ssz = sz[srow];
  const float* xp = xres + (size_t)srow * 1024;
  float* op = xm + (size_t)orow * 1024;
  const int c = t * 4;
  float4 v = *(const float4*)(xp + c);
  v.x *= ssz; v.y *= ssz; v.z *= ssz; v.w *= ssz;
  *(float4*)(op + c) = v;
  if (t == 0) sizem[orow] = ssz;
}

// ---------------- scatter-add merged src tokens into dst rows -------------
__global__ __launch_bounds__(256) void merge_add_kernel(
    const float* __restrict__ xres, const float* __restrict__ sz,
    const int* __restrict__ mask, const int* __restrict__ node,
    float* __restrict__ xm, float* __restrict__ sizem, int U)
{
  const int i = blockIdx.x;
  if (!mask[i]) return;
  const int t = threadIdx.x;
  const int srow = 2 * i;
  const int orow = U + node[i];
  const float ssz = sz[srow];
  const float* xp = xres + (size_t)srow * 1024;
  float* op = xm + (size_t)orow * 1024;
  for (int c = t; c < 1024; c += 256)
    atomicAdd(op + c, xp[c] * ssz);
  if (t == 0) atomicAdd(sizem + orow, ssz);
}

extern "C" void kernel_launch(void* const* d_in, const int* in_sizes, int n_in,
                              void* d_out, int out_size, void* d_ws, size_t ws_size,
                              hipStream_t stream) {
  const float* x      = (const float*)d_in[0];
  const float* sz     = (const float*)d_in[1];
  const float* qkv_w  = (const float*)d_in[2];
  const float* proj_w = (const float*)d_in[3];
  const float* proj_b = (const float*)d_in[4];
  const float* ln1_g  = (const float*)d_in[5];
  const float* ln1_b  = (const float*)d_in[6];
  const float* ln2_g  = (const float*)d_in[7];
  const float* ln2_b  = (const float*)d_in[8];
  const float* fc1_w  = (const float*)d_in[9];
  const float* fc1_b  = (const float*)d_in[10];
  const float* fc2_w  = (const float*)d_in[11];
  const float* fc2_b  = (const float*)d_in[12];
  const float* thr    = (const float*)d_in[13];

  const int M = out_size / 1025;
  const int U = M - 1024;
  const size_t MB = 1u << 20;
  const size_t KB = 1u << 10;

  // workspace layout (ws = 256 MiB):
  //  [0,6)   w_qkvT          [6,7)   wbar/met/mask/node
  //  [7,7.25) lpart          [8,10)  w_projT
  //  [10,22) b_qkv -> b_xa[10,14) -> b_xm[10,18)
  //  [22,30) b_xres          [30,34) b_h (dead after QKV GEMM)
  //  [71,79) w_fc1T  [79,87) w_fc2T  [87,104) b_g
  //  [104,108) b_h2  [108,142) b_facc  [142,146) vt  [146,162) opart
  char* ws = (char*)d_ws;
  u16*   w_qkvT  = (u16*)(ws + 0);
  float* b_wbar  = (float*)(ws + 6 * MB);
  float* b_met   = (float*)(ws + 6 * MB + 256 * KB);
  int*   b_mask  = (int*)(ws + 6 * MB + 768 * KB);
  int*   b_node  = b_mask + 1024;
  float* b_szm   = (float*)(b_node + 1024);
  float* b_lpart = (float*)(ws + 7 * MB);            // 2 x 128KB slices
  u16*   w_projT = (u16*)(ws + 8 * MB);
  u16*   b_qkv   = (u16*)(ws + 10 * MB);
  u16*   b_xa    = (u16*)(ws + 10 * MB);   // over dead b_qkv (after attn)
  float* b_xm    = (float*)(ws + 10 * MB);   // over dead b_xa (after proj)
  float* b_xres  = (float*)(ws + 22 * MB);
  u16*   b_h     = (u16*)(ws + 30 * MB);
  u16*   w_fc1T  = (u16*)(ws + 71 * MB);
  u16*   w_fc2T  = (u16*)(ws + 79 * MB);
  u16*   b_g     = (u16*)(ws + 87 * MB);
  u16*   b_h2    = (u16*)(ws + 104 * MB);
  float* b_facc  = (float*)(ws + 108 * MB);  // 4 partitioned slices
  u16*   b_vt    = (u16*)(ws + 142 * MB);    // written by QKV GEMM
  float* b_opart = (float*)(ws + 146 * MB);  // 2 x 8MB slices

  float* outx = (float*)d_out;
  float* outs = outx + (size_t)M * 1024;

  // 1. tiny wbar launch (must precede fused_pre: its metric blocks read it)
  wbar_kernel<<<256, 256, 0, stream>>>(qkv_w, b_wbar);
  // 2. fused opening launch: metric(inline-LN) + LN1 + ALL weight converts
  fused_pre_kernel<<<14848, 256, 0, stream>>>(
      x, ln1_g, ln1_b, b_h,
      qkv_w, w_qkvT, proj_w, w_projT, fc1_w, w_fc1T, fc2_w, w_fc2T,
      b_wbar, b_met);
  // 3. pure QKV GEMM; V-third blocks store TRANSPOSED into b_vt
  gemm_mfma<128, 64, 1, false, false, false, true, true><<<dim3(48, 16), 256, 0, stream>>>(
      b_h, w_qkvT, nullptr, (const float*)b_vt, b_qkv, 2048, 3072, 1024);
  // 4. MFMA attention with XCD-localized K/V sharing (1D swizzled grid)
  attn_mfma<2><<<1024, 256, 0, stream>>>(b_qkv, b_vt, sz, b_opart, b_lpart);
  // 5. fused attn-normalize + merge-score (independent, packed)
  norm_score_kernel<<<2304, 256, 0, stream>>>(b_opart, b_lpart, b_xa, b_met, thr, b_mask, b_node);
  // 6. proj GEMM + bias + residual(x) -> xres fp32 — 512 blocks
  gemm_mfma<64, 64, 1, true, false, true, false><<<dim3(16, 32), 256, 0, stream>>>(
      b_xa, w_projT, proj_b, x, b_xres, 2048, 1024, 1024);
  // 7. build merged rows (scan folded in)
  build_kernel<<<2048, 256, 0, stream>>>(b_xres, sz, b_mask, b_xm, b_szm, U);
  // 8. scatter-add merged src tokens
  merge_add_kernel<<<1024, 256, 0, stream>>>(b_xres, sz, b_mask, b_node, b_xm, b_szm, U);
  // 9. fused divide + LN2 (one block per row): outx, outs, h2
  divide_ln2_kernel<<<M, 256, 0, stream>>>(b_xm, b_szm, ln2_g, ln2_b, outx, outs, b_h2);
  // 10. fc1 + bias + exact GELU -> bf16 — 768 blocks
  gemm_mfma<128, 64, 1, true, true, false, true><<<dim3(64, (M + 127) / 128), 256, 0, stream>>>(
      b_h2, w_fc1T, fc1_b, nullptr, b_g, M, 4096, 1024);
  // 11. fc2 split-K=4, partitioned slices (no memset, no atomics)
  gemm_mfma<128, 64, 4, false, false, false, false><<<dim3(16, (M + 127) / 128, 4), 256, 0, stream>>>(
      b_g, w_fc2T, nullptr, nullptr, b_facc, M, 1024, 4096);
  // 12. fc2 epilogue: outx += sum(4 slices) + bias (residual in-place)
  splitk_epilogue_kernel<<<(M * 256 + 255) / 256, 256, 0, stream>>>(
      b_facc, fc2_b, outx, M);
  (void)in_sizes; (void)n_in; (void)ws_size;
}